// Round 5
// baseline (334.921 us; speedup 1.0000x reference)
//
#include <hip/hip_runtime.h>
#include <stdint.h>

// Permutohedral splat via replicated counting-sort + shfl-broadcast segmented reduce.
// N=262144 points, D=3, V=64, CAPACITY=2^20, table [CAPACITY,65] f32.
// Round 5: replace runtime hipMemsetAsync fills (157 us @ 1.7 TB/s, occupancy-
// limited rocclr kernel) with grid-stride uint4 zero-fill kernels.

#define CAPACITY (1u << 20)
#define TBL_W 65
#define CHUNK 64

// ---------------- zero fill (uint4 streaming stores) ----------------
__global__ __launch_bounds__(256) void k_fill0(uint4* __restrict__ p, size_t n4)
{
    size_t i = (size_t)blockIdx.x * blockDim.x + threadIdx.x;
    const size_t stride = (size_t)gridDim.x * blockDim.x;
    const uint4 z = make_uint4(0u, 0u, 0u, 0u);
    for (; i < n4; i += stride) p[i] = z;
}

// ---------------- lattice math (validated round 0/1) ----------------
__device__ __forceinline__ void lattice_point(const float* __restrict__ pos, int point,
                                              uint32_t h[4], float w[4])
{
    const float scale0 = 2.3094010767585034f;
    const float scale1 = 1.3333333333333333f;
    const float scale2 = 0.9428090415820634f;

    const float cf0 = pos[point * 3 + 0] * scale0;
    const float cf1 = pos[point * 3 + 1] * scale1;
    const float cf2 = pos[point * 3 + 2] * scale2;

    const float t1 = cf2 + cf1;
    float elev[4];
    elev[0] = t1 + cf0;
    elev[1] = t1 - cf0;
    elev[2] = cf2 - 2.0f * cf1;
    elev[3] = -3.0f * cf2;

    float rem0[4];
    float rd_s = 0.0f;
#pragma unroll
    for (int j = 0; j < 4; ++j) {
        float rd = rintf(elev[j] * 0.25f);
        rem0[j] = rd * 4.0f;
        rd_s += rd;
    }
    const int rd_sum = (int)rd_s;

    float diff[4];
#pragma unroll
    for (int j = 0; j < 4; ++j) diff[j] = elev[j] - rem0[j];

    int rank[4];
#pragma unroll
    for (int i = 0; i < 4; ++i) {
        int r = 0;
#pragma unroll
        for (int j = 0; j < 4; ++j) {
            if (diff[j] > diff[i] || (diff[j] == diff[i] && j < i)) r++;
        }
        rank[i] = r + rd_sum;
    }

#pragma unroll
    for (int i = 0; i < 4; ++i) {
        if (rank[i] < 0)      { rank[i] += 4; rem0[i] += 4.0f; }
        else if (rank[i] > 3) { rank[i] -= 4; rem0[i] -= 4.0f; }
    }

    float delta[4];
#pragma unroll
    for (int i = 0; i < 4; ++i) delta[i] = (elev[i] - rem0[i]) * 0.25f;

    float b[5] = {0.f, 0.f, 0.f, 0.f, 0.f};
#pragma unroll
    for (int i = 0; i < 4; ++i) {
        int k1 = 3 - rank[i];
        int k2 = 4 - rank[i];
        if (k1 >= 0 && k1 < 5) b[k1] += delta[i];
        if (k2 >= 0 && k2 < 5) b[k2] -= delta[i];
    }
    w[0] = b[0] + (1.0f + b[4]);
    w[1] = b[1];
    w[2] = b[2];
    w[3] = b[3];

    const uint32_t P0 = 2654435761u, P1 = 805459861u, P2 = 3674653429u;
    const int k0  = (int)rem0[0];
    const int k1i = (int)rem0[1];
    const int k2i = (int)rem0[2];

#pragma unroll
    for (int r = 0; r < 4; ++r) {
        int o0 = (rank[0] < 4 - r) ? r : r - 4;
        int o1 = (rank[1] < 4 - r) ? r : r - 4;
        int o2 = (rank[2] < 4 - r) ? r : r - 4;
        uint32_t hh = (uint32_t)(k0 + o0)  * P0
                    + (uint32_t)(k1i + o1) * P1
                    + (uint32_t)(k2i + o2) * P2;
        h[r] = hh & (CAPACITY - 1u);
    }
}

// ---------------- pipeline kernels ----------------
__global__ __launch_bounds__(256) void k_hist(const float* __restrict__ pos,
                                              uint32_t* __restrict__ counts,
                                              int n, int Rmask)
{
    int p = blockIdx.x * blockDim.x + threadIdx.x;
    if (p >= n) return;
    uint32_t h[4]; float w[4];
    lattice_point(pos, p, h, w);
    const size_t repBase = (size_t)(p & Rmask) * CAPACITY;
#pragma unroll
    for (int r = 0; r < 4; ++r) atomicAdd(&counts[repBase + h[r]], 1u);
}

__global__ __launch_bounds__(256) void k_blocksum(const uint32_t* __restrict__ counts,
                                                  uint32_t* __restrict__ partials)
{
    __shared__ uint32_t s[256];
    const int b = blockIdx.x, t = threadIdx.x;
    uint4 v = ((const uint4*)(counts + (size_t)b * 1024))[t];
    s[t] = v.x + v.y + v.z + v.w;
    __syncthreads();
    for (int o = 128; o > 0; o >>= 1) {
        if (t < o) s[t] += s[t + o];
        __syncthreads();
    }
    if (t == 0) partials[b] = s[0];
}

// Exclusive scan of npart (= 1024*R <= 8192) partials, single block of 1024.
__global__ __launch_bounds__(1024) void k_scanpartials(uint32_t* __restrict__ partials,
                                                       int npart)
{
    __shared__ uint32_t s[1024];
    const int t = threadIdx.x;
    const int k = npart >> 10;           // elems per thread (1..8)
    uint32_t v[8];
    uint32_t tot = 0;
    for (int j = 0; j < k; ++j) { v[j] = partials[t * k + j]; tot += v[j]; }
    s[t] = tot;
    __syncthreads();
    for (int o = 1; o < 1024; o <<= 1) {
        uint32_t x = s[t];
        uint32_t y = (t >= o) ? s[t - o] : 0u;
        __syncthreads();
        s[t] = x + y;
        __syncthreads();
    }
    uint32_t run = (t > 0) ? s[t - 1] : 0u;
    for (int j = 0; j < k; ++j) {
        uint32_t tmp = v[j];
        partials[t * k + j] = run;
        run += tmp;
    }
}

// Fused: per-bin exclusive offsets + chunked worklist emission.
// One global cursor atomicAdd PER BLOCK (LDS-aggregated), not per bin.
__global__ __launch_bounds__(256) void k_offsets_worklist(
    const uint32_t* __restrict__ counts,
    const uint32_t* __restrict__ partials,
    uint32_t* __restrict__ offsets,
    uint4* __restrict__ work,
    uint32_t* __restrict__ cursor,
    uint32_t wcap)
{
    __shared__ uint32_t s[256];
    __shared__ uint32_t wbase;
    const int b = blockIdx.x, t = threadIdx.x;
    uint4 v = ((const uint4*)(counts + (size_t)b * 1024))[t];
    const uint32_t s4 = v.x + v.y + v.z + v.w;
    s[t] = s4;
    __syncthreads();
    for (int o = 1; o < 256; o <<= 1) {
        uint32_t x = s[t];
        uint32_t y = (t >= o) ? s[t - o] : 0u;
        __syncthreads();
        s[t] = x + y;
        __syncthreads();
    }
    const uint32_t texcl = ((t > 0) ? s[t - 1] : 0u) + partials[b];
    uint4 o4;
    o4.x = texcl;
    o4.y = texcl + v.x;
    o4.z = o4.y + v.y;
    o4.w = o4.z + v.z;
    ((uint4*)(offsets + (size_t)b * 1024))[t] = o4;

    // chunk counts for this thread's 4 bins
    const uint32_t c0 = (v.x + CHUNK - 1) / CHUNK;
    const uint32_t c1 = (v.y + CHUNK - 1) / CHUNK;
    const uint32_t c2 = (v.z + CHUNK - 1) / CHUNK;
    const uint32_t c3 = (v.w + CHUNK - 1) / CHUNK;
    const uint32_t nch = c0 + c1 + c2 + c3;
    __syncthreads();                 // protect s[] reuse
    s[t] = nch;
    __syncthreads();
    for (int o = 1; o < 256; o <<= 1) {
        uint32_t x = s[t];
        uint32_t y = (t >= o) ? s[t - o] : 0u;
        __syncthreads();
        s[t] = x + y;
        __syncthreads();
    }
    if (t == 255) wbase = (s[255] > 0) ? atomicAdd(cursor, s[255]) : 0u;
    __syncthreads();
    if (nch == 0) return;
    uint32_t idx = wbase + ((t > 0) ? s[t - 1] : 0u);

    const uint32_t lin0 = (uint32_t)b * 1024u + (uint32_t)t * 4u;
    const uint32_t cnts[4]   = { v.x, v.y, v.z, v.w };
    const uint32_t starts[4] = { o4.x, o4.y, o4.z, o4.w };
#pragma unroll
    for (int j = 0; j < 4; ++j) {
        uint32_t cnt = cnts[j];
        if (cnt == 0) continue;
        const uint32_t h = (lin0 + j) & (CAPACITY - 1u);
        uint32_t cs = starts[j];
        const uint32_t ce_all = cs + cnt;
        while (cs < ce_all) {
            uint32_t ce = min(cs + (uint32_t)CHUNK, ce_all);
            if (idx < wcap) work[idx] = make_uint4(h, cs, ce, 0u);
            ++idx;
            cs = ce;
        }
    }
}

// Scatter (w, pid) into sorted position; atomicSub consumes counts.
__global__ __launch_bounds__(256) void k_scatter(const float* __restrict__ pos,
                                                 const uint32_t* __restrict__ offsets,
                                                 uint32_t* __restrict__ counts,
                                                 uint2* __restrict__ wp_s,
                                                 int n, int Rmask)
{
    int p = blockIdx.x * blockDim.x + threadIdx.x;
    if (p >= n) return;
    uint32_t h[4]; float w[4];
    lattice_point(pos, p, h, w);
    const size_t repBase = (size_t)(p & Rmask) * CAPACITY;
#pragma unroll
    for (int r = 0; r < 4; ++r) {
        const size_t lin = repBase + h[r];
        uint32_t slot = atomicSub(&counts[lin], 1u) - 1u;
        uint32_t dst  = offsets[lin] + slot;
        uint2 wp;
        wp.x = __float_as_uint(w[r]);
        wp.y = (uint32_t)p;
        wp_s[dst] = wp;
    }
}

// One wave per chunk (<=64 entries). Coalesced wp load (lane e = entry e),
// shfl-broadcast; 8-deep independent vals gathers; one atomic flush per chunk.
__global__ __launch_bounds__(256) void k_reduce(const uint4* __restrict__ work,
                                                const uint32_t* __restrict__ cursor,
                                                const uint2* __restrict__ wp_s,
                                                const float* __restrict__ vals,
                                                float* __restrict__ table,
                                                uint32_t wcap)
{
    const int gtid   = blockIdx.x * blockDim.x + threadIdx.x;
    const int wid    = gtid >> 6;
    const int lane   = threadIdx.x & 63;
    const int nwaves = (gridDim.x * blockDim.x) >> 6;
    const uint32_t nwork = min(*cursor, wcap);

    for (uint32_t it = wid; it < nwork; it += nwaves) {
        const uint4 wi = work[it];
        const uint32_t h   = wi.x;
        const uint32_t cnt = wi.z - wi.y;

        uint2 wp = make_uint2(0u, 0u);
        if (lane < (int)cnt) wp = wp_s[wi.y + lane];
        const float    mywgt = __uint_as_float(wp.x);
        const int      mypid = (int)wp.y;

        float acc = 0.0f, acc1 = 0.0f;
        uint32_t e = 0;
        for (; e + 8 <= cnt; e += 8) {
#pragma unroll
            for (int j = 0; j < 8; ++j) {
                const float wj = __shfl(mywgt, (int)(e + j));
                const int   pj = __shfl(mypid, (int)(e + j));
                acc  += wj * vals[(size_t)pj * 64 + lane];
                acc1 += wj;
            }
        }
        for (; e < cnt; ++e) {
            const float wj = __shfl(mywgt, (int)e);
            const int   pj = __shfl(mypid, (int)e);
            acc  += wj * vals[(size_t)pj * 64 + lane];
            acc1 += wj;
        }
        atomicAdd(&table[(size_t)h * TBL_W + lane], acc);
        if (lane == 0) atomicAdd(&table[(size_t)h * TBL_W + 64], acc1);
    }
}

// ---------------- round-0 fallback ----------------
__global__ __launch_bounds__(256) void splat_fallback(const float* __restrict__ pos,
                                                      const float* __restrict__ vals,
                                                      float* __restrict__ table, int n)
{
    const int gtid  = blockIdx.x * blockDim.x + threadIdx.x;
    const int point = gtid >> 6;
    const int lane  = threadIdx.x & 63;
    if (point >= n) return;
    uint32_t h[4]; float w[4];
    lattice_point(pos, point, h, w);
    const float v = vals[(size_t)point * 64 + lane];
#pragma unroll
    for (int r = 0; r < 4; ++r)
        atomicAdd(&table[(size_t)h[r] * TBL_W + lane], w[r] * v);
    if (lane == 0) {
#pragma unroll
        for (int r = 0; r < 4; ++r)
            atomicAdd(&table[(size_t)h[r] * TBL_W + 64], w[r]);
    }
}

// ---------------- host launch ----------------
extern "C" void kernel_launch(void* const* d_in, const int* in_sizes, int n_in,
                              void* d_out, int out_size, void* d_ws, size_t ws_size,
                              hipStream_t stream) {
    const float* pos  = (const float*)d_in[0];
    const float* vals = (const float*)d_in[1];
    float* table      = (float*)d_out;

    const int n = in_sizes[0] / 3;        // 262144
    const uint32_t M = (uint32_t)n * 4;   // 1,048,576

    // Zero output table with our own wide-store fill (runtime memset is
    // occupancy-limited: 157 us @ 1.7 TB/s; this should be ~50 us).
    {
        const size_t n4 = ((size_t)out_size * sizeof(float)) / 16;  // 17,039,360
        k_fill0<<<4096, 256, 0, stream>>>((uint4*)d_out, n4);
    }

    // Choose replication R; worklist capacity is a true upper bound.
    int R = 0;
    uint32_t wcap = 0;
    size_t offCnt = 0, offCur = 0, offOff = 0, offPart = 0, offWp = 0, offWork = 0;
    const uint32_t wcapFull = M + M / CHUNK;
    for (int tryR = 8; tryR >= 1; tryR >>= 1) {
        size_t L = (size_t)CAPACITY * tryR;
        size_t o0 = 0;                       // counts: L*4
        size_t o1 = o0 + L * 4;              // cursor: 64
        size_t o2 = o1 + 64;                 // offsets: L*4
        size_t o3 = o2 + L * 4;              // partials: (L/1024)*4
        size_t o4 = o3 + (L / 1024) * 4;     // wp_s: M*8
        size_t o5 = o4 + (size_t)M * 8;      // work: wcap*16
        size_t need = o5 + (size_t)wcapFull * 16;
        if (need <= ws_size) {
            R = tryR; wcap = wcapFull;
            offCnt = o0; offCur = o1; offOff = o2; offPart = o3; offWp = o4; offWork = o5;
            break;
        }
    }

    if (!R) {
        const int blocks = (n * 64 + 255) / 256;
        splat_fallback<<<blocks, 256, 0, stream>>>(pos, vals, table, n);
        return;
    }

    uint8_t* ws = (uint8_t*)d_ws;
    uint32_t* counts   = (uint32_t*)(ws + offCnt);
    uint32_t* cursor   = (uint32_t*)(ws + offCur);
    uint32_t* offsets  = (uint32_t*)(ws + offOff);
    uint32_t* partials = (uint32_t*)(ws + offPart);
    uint2*    wp_s     = (uint2*)   (ws + offWp);
    uint4*    work     = (uint4*)   (ws + offWork);

    const uint32_t L = (uint32_t)CAPACITY * R;
    const int Rmask = R - 1;

    // Zero counts + cursor (region is 16B-divisible: L*4 + 64).
    {
        const size_t n4 = ((size_t)L * 4 + 64) / 16;
        k_fill0<<<2048, 256, 0, stream>>>((uint4*)ws, n4);
    }

    const int ptBlocks = (n + 255) / 256;
    k_hist<<<ptBlocks, 256, 0, stream>>>(pos, counts, n, Rmask);

    const int scanBlocks = L / 1024;
    k_blocksum        <<<scanBlocks, 256,  0, stream>>>(counts, partials);
    k_scanpartials    <<<1,          1024, 0, stream>>>(partials, scanBlocks);
    k_offsets_worklist<<<scanBlocks, 256,  0, stream>>>(counts, partials, offsets,
                                                        work, cursor, wcap);

    k_scatter<<<ptBlocks, 256, 0, stream>>>(pos, offsets, counts, wp_s, n, Rmask);

    k_reduce<<<4096, 256, 0, stream>>>(work, cursor, wp_s, vals, table, wcap);
}

// Round 6
// 128.716 us; speedup vs baseline: 2.6020x; 2.6020x over previous
//
#include <hip/hip_runtime.h>
#include <stdint.h>

// Permutohedral splat, round 6: counting-sort POINTS by simplex-cell key
// (262k records, 4B payload), then one-pass reduce that reads each vals row
// exactly once and flushes 4x65 atomics per cell-run boundary.
// N=262144, D=3, V=64, CAPACITY=2^20, table [CAPACITY,65] f32.

#define CAPACITY (1u << 20)
#define KCAP     (1u << 20)
#define TBL_W 65
#define CHUNK 64

// ---------------- lattice math (validated rounds 0-5) ----------------
// Outputs: h[4] vertex hashes, w[4] barycentric weights, cell key.
__device__ __forceinline__ void lattice_all(const float* __restrict__ pos, int point,
                                            uint32_t h[4], float w[4], uint32_t* keyOut)
{
    const float scale0 = 2.3094010767585034f;
    const float scale1 = 1.3333333333333333f;
    const float scale2 = 0.9428090415820634f;

    const float cf0 = pos[point * 3 + 0] * scale0;
    const float cf1 = pos[point * 3 + 1] * scale1;
    const float cf2 = pos[point * 3 + 2] * scale2;

    const float t1 = cf2 + cf1;
    float elev[4];
    elev[0] = t1 + cf0;
    elev[1] = t1 - cf0;
    elev[2] = cf2 - 2.0f * cf1;
    elev[3] = -3.0f * cf2;

    float rem0[4];
    float rd_s = 0.0f;
#pragma unroll
    for (int j = 0; j < 4; ++j) {
        float rd = rintf(elev[j] * 0.25f);
        rem0[j] = rd * 4.0f;
        rd_s += rd;
    }
    const int rd_sum = (int)rd_s;

    float diff[4];
#pragma unroll
    for (int j = 0; j < 4; ++j) diff[j] = elev[j] - rem0[j];

    int rank[4];
#pragma unroll
    for (int i = 0; i < 4; ++i) {
        int r = 0;
#pragma unroll
        for (int j = 0; j < 4; ++j) {
            if (diff[j] > diff[i] || (diff[j] == diff[i] && j < i)) r++;
        }
        rank[i] = r + rd_sum;
    }

#pragma unroll
    for (int i = 0; i < 4; ++i) {
        if (rank[i] < 0)      { rank[i] += 4; rem0[i] += 4.0f; }
        else if (rank[i] > 3) { rank[i] -= 4; rem0[i] -= 4.0f; }
    }

    float delta[4];
#pragma unroll
    for (int i = 0; i < 4; ++i) delta[i] = (elev[i] - rem0[i]) * 0.25f;

    float b[5] = {0.f, 0.f, 0.f, 0.f, 0.f};
#pragma unroll
    for (int i = 0; i < 4; ++i) {
        int k1 = 3 - rank[i];
        int k2 = 4 - rank[i];
        if (k1 >= 0 && k1 < 5) b[k1] += delta[i];
        if (k2 >= 0 && k2 < 5) b[k2] -= delta[i];
    }
    w[0] = b[0] + (1.0f + b[4]);
    w[1] = b[1];
    w[2] = b[2];
    w[3] = b[3];

    const uint32_t P0 = 2654435761u, P1 = 805459861u, P2 = 3674653429u;
    const int k0  = (int)rem0[0];
    const int k1i = (int)rem0[1];
    const int k2i = (int)rem0[2];

#pragma unroll
    for (int r = 0; r < 4; ++r) {
        int o0 = (rank[0] < 4 - r) ? r : r - 4;
        int o1 = (rank[1] < 4 - r) ? r : r - 4;
        int o2 = (rank[2] < 4 - r) ? r : r - 4;
        uint32_t hh = (uint32_t)(k0 + o0)  * P0
                    + (uint32_t)(k1i + o1) * P1
                    + (uint32_t)(k2i + o2) * P2;
        h[r] = hh & (CAPACITY - 1u);
    }

    // Cell key: base-vertex hash mixed with rank permutation (6 bits).
    const uint32_t pidx = (uint32_t)(rank[0] * 16 + rank[1] * 4 + rank[2]);
    uint32_t key = (uint32_t)k0 * P0 + (uint32_t)k1i * P1 + (uint32_t)k2i * P2
                 + pidx * 0x9E3779B9u;
    *keyOut = key & (KCAP - 1u);
}

// ---------------- pipeline kernels ----------------
__global__ __launch_bounds__(256) void k_hist(const float* __restrict__ pos,
                                              uint32_t* __restrict__ counts,
                                              uint32_t* __restrict__ keys, int n)
{
    int p = blockIdx.x * blockDim.x + threadIdx.x;
    if (p >= n) return;
    uint32_t h[4]; float w[4]; uint32_t key;
    lattice_all(pos, p, h, w, &key);
    keys[p] = key;
    atomicAdd(&counts[key], 1u);
}

__global__ __launch_bounds__(256) void k_blocksum(const uint32_t* __restrict__ counts,
                                                  uint32_t* __restrict__ partials)
{
    __shared__ uint32_t s[256];
    const int b = blockIdx.x, t = threadIdx.x;
    uint4 v = ((const uint4*)(counts + (size_t)b * 1024))[t];
    s[t] = v.x + v.y + v.z + v.w;
    __syncthreads();
    for (int o = 128; o > 0; o >>= 1) {
        if (t < o) s[t] += s[t + o];
        __syncthreads();
    }
    if (t == 0) partials[b] = s[0];
}

__global__ __launch_bounds__(1024) void k_scanpartials(uint32_t* __restrict__ partials,
                                                       int npart)
{
    __shared__ uint32_t s[1024];
    const int t = threadIdx.x;
    const int k = npart >> 10;           // 1 here
    uint32_t v[8];
    uint32_t tot = 0;
    for (int j = 0; j < k; ++j) { v[j] = partials[t * k + j]; tot += v[j]; }
    s[t] = tot;
    __syncthreads();
    for (int o = 1; o < 1024; o <<= 1) {
        uint32_t x = s[t];
        uint32_t y = (t >= o) ? s[t - o] : 0u;
        __syncthreads();
        s[t] = x + y;
        __syncthreads();
    }
    uint32_t run = (t > 0) ? s[t - 1] : 0u;
    for (int j = 0; j < k; ++j) {
        uint32_t tmp = v[j];
        partials[t * k + j] = run;
        run += tmp;
    }
}

__global__ __launch_bounds__(256) void k_offsets(const uint32_t* __restrict__ counts,
                                                 const uint32_t* __restrict__ partials,
                                                 uint32_t* __restrict__ offsets)
{
    __shared__ uint32_t s[256];
    const int b = blockIdx.x, t = threadIdx.x;
    uint4 v = ((const uint4*)(counts + (size_t)b * 1024))[t];
    s[t] = v.x + v.y + v.z + v.w;
    __syncthreads();
    for (int o = 1; o < 256; o <<= 1) {
        uint32_t x = s[t];
        uint32_t y = (t >= o) ? s[t - o] : 0u;
        __syncthreads();
        s[t] = x + y;
        __syncthreads();
    }
    uint32_t texcl = ((t > 0) ? s[t - 1] : 0u) + partials[b];
    uint4 o4;
    o4.x = texcl;
    o4.y = texcl + v.x;
    o4.z = o4.y + v.y;
    o4.w = o4.z + v.z;
    ((uint4*)(offsets + (size_t)b * 1024))[t] = o4;
}

// Place pid into cell-sorted order (atomicSub consumes counts).
__global__ __launch_bounds__(256) void k_scatter(const uint32_t* __restrict__ keys,
                                                 const uint32_t* __restrict__ offsets,
                                                 uint32_t* __restrict__ counts,
                                                 uint32_t* __restrict__ sorted, int n)
{
    int p = blockIdx.x * blockDim.x + threadIdx.x;
    if (p >= n) return;
    const uint32_t key = keys[p];
    uint32_t slot = atomicSub(&counts[key], 1u) - 1u;
    sorted[offsets[key] + slot] = (uint32_t)p;
}

// One wave per 64 sorted points. Lane e recomputes lattice for its entry;
// run-detection by exact h[4] comparison (shfl-broadcast, wave-uniform);
// each vals row read exactly once; flush 4x65 atomics per run boundary.
__global__ __launch_bounds__(256) void k_reduce(const uint32_t* __restrict__ sorted,
                                                const float* __restrict__ pos,
                                                const float* __restrict__ vals,
                                                float* __restrict__ table, int N)
{
    const int gtid = blockIdx.x * blockDim.x + threadIdx.x;
    const int wid  = gtid >> 6;
    const int lane = threadIdx.x & 63;
    const int base = wid * CHUNK;
    if (base >= N) return;
    const int cnt = min(CHUNK, N - base);

    const int e = (lane < cnt) ? lane : 0;
    const int mypid = (int)sorted[base + e];

    uint32_t mh[4]; float mw[4]; uint32_t dummyKey;
    lattice_all(pos, mypid, mh, mw, &dummyKey);

    uint32_t h0p = __shfl(mh[0], 0);
    uint32_t h1p = __shfl(mh[1], 0);
    uint32_t h2p = __shfl(mh[2], 0);
    uint32_t h3p = __shfl(mh[3], 0);

    float acc0 = 0.f, acc1 = 0.f, acc2 = 0.f, acc3 = 0.f;   // channel sums
    float aW0 = 0.f, aW1 = 0.f, aW2 = 0.f, aW3 = 0.f;       // homogeneous sums

    for (int eb = 0; eb < cnt; eb += 8) {
        const int m = min(8, cnt - eb);
        float row[8];
#pragma unroll
        for (int j = 0; j < 8; ++j) {
            const int pj = __shfl(mypid, (eb + j) & (CHUNK - 1));
            row[j] = (j < m) ? vals[(size_t)pj * 64 + lane] : 0.f;
        }
#pragma unroll
        for (int j = 0; j < 8; ++j) {
            if (j >= m) break;
            const int src = eb + j;
            const uint32_t h0c = __shfl(mh[0], src);
            const uint32_t h1c = __shfl(mh[1], src);
            const uint32_t h2c = __shfl(mh[2], src);
            const uint32_t h3c = __shfl(mh[3], src);
            if ((h0c != h0p) | (h1c != h1p) | (h2c != h2p) | (h3c != h3p)) {
                // flush previous run (wave-uniform branch)
                atomicAdd(&table[(size_t)h0p * TBL_W + lane], acc0);
                atomicAdd(&table[(size_t)h1p * TBL_W + lane], acc1);
                atomicAdd(&table[(size_t)h2p * TBL_W + lane], acc2);
                atomicAdd(&table[(size_t)h3p * TBL_W + lane], acc3);
                if (lane == 0) {
                    atomicAdd(&table[(size_t)h0p * TBL_W + 64], aW0);
                    atomicAdd(&table[(size_t)h1p * TBL_W + 64], aW1);
                    atomicAdd(&table[(size_t)h2p * TBL_W + 64], aW2);
                    atomicAdd(&table[(size_t)h3p * TBL_W + 64], aW3);
                }
                acc0 = acc1 = acc2 = acc3 = 0.f;
                aW0 = aW1 = aW2 = aW3 = 0.f;
                h0p = h0c; h1p = h1c; h2p = h2c; h3p = h3c;
            }
            const float w0 = __shfl(mw[0], src);
            const float w1 = __shfl(mw[1], src);
            const float w2 = __shfl(mw[2], src);
            const float w3 = __shfl(mw[3], src);
            acc0 += w0 * row[j];
            acc1 += w1 * row[j];
            acc2 += w2 * row[j];
            acc3 += w3 * row[j];
            aW0 += w0; aW1 += w1; aW2 += w2; aW3 += w3;
        }
    }
    // final flush
    atomicAdd(&table[(size_t)h0p * TBL_W + lane], acc0);
    atomicAdd(&table[(size_t)h1p * TBL_W + lane], acc1);
    atomicAdd(&table[(size_t)h2p * TBL_W + lane], acc2);
    atomicAdd(&table[(size_t)h3p * TBL_W + lane], acc3);
    if (lane == 0) {
        atomicAdd(&table[(size_t)h0p * TBL_W + 64], aW0);
        atomicAdd(&table[(size_t)h1p * TBL_W + 64], aW1);
        atomicAdd(&table[(size_t)h2p * TBL_W + 64], aW2);
        atomicAdd(&table[(size_t)h3p * TBL_W + 64], aW3);
    }
}

// ---------------- fallback (ws too small) ----------------
__global__ __launch_bounds__(256) void splat_fallback(const float* __restrict__ pos,
                                                      const float* __restrict__ vals,
                                                      float* __restrict__ table, int n)
{
    const int gtid  = blockIdx.x * blockDim.x + threadIdx.x;
    const int point = gtid >> 6;
    const int lane  = threadIdx.x & 63;
    if (point >= n) return;
    uint32_t h[4]; float w[4]; uint32_t key;
    lattice_all(pos, point, h, w, &key);
    const float v = vals[(size_t)point * 64 + lane];
#pragma unroll
    for (int r = 0; r < 4; ++r)
        atomicAdd(&table[(size_t)h[r] * TBL_W + lane], w[r] * v);
    if (lane == 0) {
#pragma unroll
        for (int r = 0; r < 4; ++r)
            atomicAdd(&table[(size_t)h[r] * TBL_W + 64], w[r]);
    }
}

// ---------------- host launch ----------------
extern "C" void kernel_launch(void* const* d_in, const int* in_sizes, int n_in,
                              void* d_out, int out_size, void* d_ws, size_t ws_size,
                              hipStream_t stream) {
    const float* pos  = (const float*)d_in[0];
    const float* vals = (const float*)d_in[1];
    float* table      = (float*)d_out;

    const int n = in_sizes[0] / 3;        // 262144

    // Zero output table (runtime fill runs ~6.8 TB/s; our own fill was not better).
    hipMemsetAsync(d_out, 0, (size_t)out_size * sizeof(float), stream);

    // Workspace layout.
    const size_t SZ_CNT  = (size_t)KCAP * 4;     // 4 MB counts
    const size_t offCnt  = 0;
    const size_t offOff  = offCnt + SZ_CNT;      // 4 MB offsets
    const size_t offPart = offOff + SZ_CNT;      // 4 KB partials
    const size_t offKeys = offPart + 4096;       // 1 MB keys
    const size_t offSort = offKeys + (size_t)n * 4;
    const size_t REQUIRED = offSort + (size_t)n * 4;

    if (ws_size < REQUIRED) {
        const int blocks = (n * 64 + 255) / 256;
        splat_fallback<<<blocks, 256, 0, stream>>>(pos, vals, table, n);
        return;
    }

    uint8_t* ws = (uint8_t*)d_ws;
    uint32_t* counts   = (uint32_t*)(ws + offCnt);
    uint32_t* offsets  = (uint32_t*)(ws + offOff);
    uint32_t* partials = (uint32_t*)(ws + offPart);
    uint32_t* keys     = (uint32_t*)(ws + offKeys);
    uint32_t* sorted   = (uint32_t*)(ws + offSort);

    hipMemsetAsync(counts, 0, SZ_CNT, stream);

    const int ptBlocks = (n + 255) / 256;               // 1024
    k_hist<<<ptBlocks, 256, 0, stream>>>(pos, counts, keys, n);

    const int scanBlocks = KCAP / 1024;                 // 1024
    k_blocksum    <<<scanBlocks, 256,  0, stream>>>(counts, partials);
    k_scanpartials<<<1,          1024, 0, stream>>>(partials, scanBlocks);
    k_offsets     <<<scanBlocks, 256,  0, stream>>>(counts, partials, offsets);

    k_scatter<<<ptBlocks, 256, 0, stream>>>(keys, offsets, counts, sorted, n);

    const int nWaves  = (n + CHUNK - 1) / CHUNK;        // 4096
    const int rBlocks = (nWaves + 3) / 4;               // 1024 (4 waves/block)
    k_reduce<<<rBlocks, 256, 0, stream>>>(sorted, pos, vals, table, n);
}